// Round 6
// baseline (1669.061 us; speedup 1.0000x reference)
//
#include <hip/hip_runtime.h>

// Problem dims
#define S_LEN 256
#define B_SZ  512
#define IN_D  512
#define HID_D 1024
#define NA    16
#define LH    256
#define MR    131072           // S*B
#define LOGOFF 2097152         // S*B*A
#define COLCAP 256
#define DEADW  1024            // t=0, active=0, resetAfter=1

typedef __attribute__((ext_vector_type(8))) short bf16x8;
typedef __attribute__((ext_vector_type(4))) short short4v;
typedef __attribute__((ext_vector_type(4))) float f32x4;

__device__ __forceinline__ unsigned short f2b(float f){
  unsigned int u = __builtin_bit_cast(unsigned int, f);
  unsigned int r = (u + 0x7fffu + ((u>>16)&1u)) >> 16;
  return (unsigned short)r;
}
__device__ __forceinline__ float b2f(unsigned short b){
  unsigned int u = ((unsigned int)b)<<16; return __builtin_bit_cast(float,u);
}
__device__ __forceinline__ float sigf(float x){
  float t = exp2f(-1.4426950408889634f*x);
  return __builtin_amdgcn_rcpf(1.0f+t);
}
__device__ __forceinline__ float tanhf_(float x){
  float t = exp2f(2.8853900817779268f*x);
  return 1.0f - 2.0f*__builtin_amdgcn_rcpf(1.0f+t);
}

#define GLDS16(g, lp) __builtin_amdgcn_global_load_lds( \
    (const __attribute__((address_space(1))) unsigned int*)(g), \
    (__attribute__((address_space(3))) unsigned int*)(lp), 16, 0, 0)

// LDS-only barrier: no vmcnt drain.
#define BARRIER_LDS() do { \
    __builtin_amdgcn_sched_barrier(0); \
    asm volatile("s_waitcnt lgkmcnt(0)" ::: "memory"); \
    __builtin_amdgcn_s_barrier(); \
    __builtin_amdgcn_sched_barrier(0); \
  } while(0)

// ---------------- prep kernels ----------------
__global__ __launch_bounds__(256) void prep_x(const float4* __restrict__ x,
                                              short4v* __restrict__ xb){
  int i = blockIdx.x*256 + threadIdx.x;
  int stride = gridDim.x*256;
  for (; i < 16777216; i += stride){
    float4 f = x[i];
    short4v o; o[0]=(short)f2b(f.x); o[1]=(short)f2b(f.y); o[2]=(short)f2b(f.z); o[3]=(short)f2b(f.w);
    xb[i] = o;
  }
}

__global__ __launch_bounds__(256) void prep_w(
    const float* __restrict__ W1, const float* __restrict__ Wih,
    const float* __restrict__ bih, const float* __restrict__ Whh,
    const float* __restrict__ bhh, const float* __restrict__ Wpi,
    const float* __restrict__ bpi, const float* __restrict__ Wv,
    const float* __restrict__ bv,
    ushort* __restrict__ W1b, ushort* __restrict__ Awb, ushort* __restrict__ Whhb,
    ushort* __restrict__ Wpvb, float* __restrict__ wr_, float* __restrict__ bsum,
    float* __restrict__ Etab, float* __restrict__ bpv){
  int i = blockIdx.x*256 + threadIdx.x;
  if (i < 524288) W1b[i] = f2b(W1[i]);
  if (i < 1048576){ int n=i>>10, k=i&1023; Awb[i] = f2b(Wih[n*1041+k]); }
  if (i < 262144) Whhb[i] = f2b(Whh[i]);
  if (i < 8192){ int r=i>>8, k=i&255;
    float v = (r<16) ? Wpi[r*256+k] : ((r==16) ? Wv[k] : 0.f);
    Wpvb[i] = f2b(v); }
  if (i < 1024){ wr_[i] = Wih[i*1041+1024]; bsum[i] = bih[i]+bhh[i]; }
  if (i < 16384){ int a=i>>10, n=i&1023; Etab[i] = Wih[n*1041+1025+a]; }
  if (i < 32) bpv[i] = (i<16) ? bpi[i] : ((i==16) ? bv[0] : 0.f);
}

// ---------------- segment builder ----------------
__global__ __launch_bounds__(256) void build_cols(const int* __restrict__ dones,
                                                  int* __restrict__ vt,
                                                  int* __restrict__ lens){
  int b = blockIdx.x*256 + threadIdx.x;
  if (b >= 512) return;
  const int colbase = (b>>1)*16 + (b&1)*8;
  int cur = 0, curpos = 0;
  for (int t = 0; t < 256; ++t){
    int isStart = (t==0) || (dones[t*512+b] != 0);
    if (isStart){
      int nc = t>>5; if (nc>7) nc=7;      // cumulative position == t
      if (nc != cur){
        lens[colbase+cur] = curpos;
        for (int j=cur+1;j<nc;++j) lens[colbase+j]=0;
        cur = nc; curpos = 0;
      }
    }
    int rstA = (t==255) || (dones[(t==255?255:(t+1))*512+b] != 0);
    vt[(colbase+cur)*COLCAP + curpos] = t | (1<<9) | (rstA<<10);
    curpos++;
  }
  lens[colbase+cur] = curpos;
  for (int j=cur+1;j<8;++j) lens[colbase+j]=0;
}

// ---------------- 128x128 bf16 GEMM (depth-2 counted-vmcnt + XCD swizzle) ----
// 3 LDS stages; iter kt: vmcnt(4) [stage kt landed, kt+1 in flight] -> barrier
// -> issue stage kt+2 -> ds_read stage kt -> MFMA (setprio) -> lgkm drain.
// Loads stay in flight ACROSS barriers (T4); never drain to 0 in steady state.
// MFMA operands swapped so each lane owns 4 consecutive n -> 8B C-stores.
template<int K, int EPI>
__global__ __launch_bounds__(256) void gemm128(
    const ushort* __restrict__ A, const ushort* __restrict__ Bm,
    ushort* __restrict__ C,
    const float* __restrict__ e0, const float* __restrict__ e1,
    const float* __restrict__ e2, const float* __restrict__ rew,
    const int* __restrict__ la){
  __shared__ ushort As[3][128*32];
  __shared__ ushort Bs[3][128*32];
  const int t = threadIdx.x;
  const int w = t>>6, l = t&63, lq = l>>4, lr = l&15;
  const int wr = w>>1, wc = w&1;
  const int lid = blockIdx.y*8 + blockIdx.x;   // dispatch-linear id (x fastest)
  const int xcd = lid & 7, j = lid >> 3;       // XCD round-robin model
  const int m0 = (xcd*128 + (j>>3))*128;
  const int n0 = (j&7)*128;

  const ushort* Ag0 = A  + (size_t)(m0 + (t>>2))*K + (t&3)*8;
  const ushort* Ag1 = Ag0 + (size_t)64*K;
  const ushort* Bg0 = Bm + (size_t)(n0 + (t>>2))*K + (t&3)*8;
  const ushort* Bg1 = Bg0 + (size_t)64*K;

  f32x4 acc[4][4] = {};
  const int aro = (wr*64 + lr)*32 + lq*8;
  const int bro = (wc*64 + lr)*32 + lq*8;
  const int NT = K/32;

#define STAGEIT(p, ko) do { \
    GLDS16(Ag0 + (ko), &As[p][t*8]); \
    GLDS16(Ag1 + (ko), &As[p][(t+256)*8]); \
    GLDS16(Bg0 + (ko), &Bs[p][t*8]); \
    GLDS16(Bg1 + (ko), &Bs[p][(t+256)*8]); \
  } while(0)

  // prologue: stage tiles 0 and 1 (8 loads in flight)
  STAGEIT(0, 0);
  STAGEIT(1, 32);

  int cur = 0, stg = 2;
  for (int kt = 0; kt < NT; ++kt){
    __builtin_amdgcn_sched_barrier(0);
    if (kt < NT-1) asm volatile("s_waitcnt vmcnt(4)" ::: "memory");
    else           asm volatile("s_waitcnt vmcnt(0)" ::: "memory");
    __builtin_amdgcn_s_barrier();
    __builtin_amdgcn_sched_barrier(0);
    if (kt+2 < NT) STAGEIT(stg, (kt+2)*32);
    const ushort* Ab = &As[cur][0];
    const ushort* Bb = &Bs[cur][0];
    bf16x8 af[4], bf[4];
    #pragma unroll
    for (int i=0;i<4;++i) af[i] = *(const bf16x8*)&Ab[aro + i*512];
    #pragma unroll
    for (int j2=0;j2<4;++j2) bf[j2] = *(const bf16x8*)&Bb[bro + j2*512];
    __builtin_amdgcn_s_setprio(1);
    #pragma unroll
    for (int i=0;i<4;++i)
      #pragma unroll
      for (int j2=0;j2<4;++j2)
        acc[i][j2] = __builtin_amdgcn_mfma_f32_16x16x32_bf16(bf[j2], af[i], acc[i][j2], 0,0,0);
    __builtin_amdgcn_s_setprio(0);
    // ensure this iter's ds_reads completed before next barrier (rule 18)
    __builtin_amdgcn_sched_barrier(0);
    asm volatile("s_waitcnt lgkmcnt(0)" ::: "memory");
    __builtin_amdgcn_sched_barrier(0);
    cur = (cur==2) ? 0 : cur+1;
    stg = (stg==2) ? 0 : stg+1;
  }

  // Swapped-operand C/D mapping: m = m0+wr*64+i*16+lr (per-lane fixed),
  // n = n0+wc*64+j2*16+lq*4+r (4 consecutive per lane) -> 8B stores.
  if (EPI == 1){
    #pragma unroll
    for (int i=0;i<4;++i){
      const int m = m0 + wr*64 + i*16 + lr;
      #pragma unroll
      for (int j2=0;j2<4;++j2){
        const int nb = n0 + wc*64 + j2*16 + lq*4;
        const float4 bn = *(const float4*)&e0[nb];
        short4v v;
        #pragma unroll
        for (int r=0;r<4;++r){
          float vv = acc[i][j2][r] + ((const float*)&bn)[r];
          vv = vv > 0.f ? vv : 0.01f*vv;
          v[r] = (short)f2b(vv);
        }
        *(short4v*)&C[(size_t)m*1024 + nb] = v;
      }
    }
  } else {
    #pragma unroll
    for (int i=0;i<4;++i){
      const int m = m0 + wr*64 + i*16 + lr;
      const float rv = rew[m];
      const int av = la[m];
      #pragma unroll
      for (int j2=0;j2<4;++j2){
        const int nb = n0 + wc*64 + j2*16 + lq*4;
        const float4 wv = *(const float4*)&e0[nb];
        const float4 bs = *(const float4*)&e1[nb];
        const float4 et = *(const float4*)&e2[(size_t)av*1024 + nb];
        short4v v;
        #pragma unroll
        for (int r=0;r<4;++r){
          float vv = acc[i][j2][r] + rv*((const float*)&wv)[r]
                   + ((const float*)&et)[r] + ((const float*)&bs)[r];
          v[r] = (short)f2b(vv);
        }
        *(short4v*)&C[(size_t)m*1024 + nb] = v;
      }
    }
  }
}

// ---------------- recurrent LSTM kernel (segment-parallel) ----------------
#define LW_FR 18
#define HB0 (8*LW_FR*1024)
__global__ __launch_bounds__(512, 2) void lstm_seq(
    const ushort* __restrict__ Whhb, const ushort* __restrict__ gx,
    ushort* __restrict__ hsout, const int* __restrict__ vt,
    const int* __restrict__ lens){
  extern __shared__ char smem[];
  ushort* wlds = (ushort*)smem;
  char* hb = smem + HB0;                 // 16 cols x 256 bf16, XOR-swizzled
  const int t = threadIdx.x, w = t>>6, l = t&63, lq = l>>4, lr = l&15;
  const int g = blockIdx.x;
  const int bcol = 2*g + (lr>>3);        // batch of column lr
  const int cgl = g*16 + lr;             // global column id

  // register weight frags: m<2 -> k0..4 ; m>=2 -> k0..5   (m = gate*2+hi)
  bf16x8 wf[8][6];
  #pragma unroll
  for (int m=0;m<8;++m){
    const size_t rb = (size_t)((m>>1)*256 + w*32 + (m&1)*16 + lr)*256 + lq*8;
    #pragma unroll
    for (int k=0;k<6;++k){
      if (k < ((m<2)?5:6)) wf[m][k] = *(const bf16x8*)&Whhb[rb + (size_t)k*32];
    }
  }
  // Pin: forbid rematerializing these loads inside the step loop.
  #pragma unroll
  for (int m=0;m<8;++m)
    #pragma unroll
    for (int k=0;k<6;++k)
      if (k < ((m<2)?5:6)) asm volatile("" : "+v"(wf[m][k]));

  // LDS weight frags: m<2 -> k5,6,7 ; m>=2 -> k6,7
  #pragma unroll
  for (int m=0;m<8;++m){
    const size_t rb = (size_t)((m>>1)*256 + w*32 + (m&1)*16 + lr)*256 + lq*8;
    #pragma unroll
    for (int kk=0;kk<3;++kk){
      if (kk < ((m<2)?3:2)){
        const int k  = (m<2)?(5+kk):(6+kk);
        const int fi = (m<2)?(m*3+kk):(6+(m-2)*2+kk);
        bf16x8 v = *(const bf16x8*)&Whhb[rb + (size_t)k*32];
        *(bf16x8*)((char*)wlds + ((w*LW_FR + fi)*1024 + l*16)) = v;
      }
    }
  }
  { bf16x8 z = {0,0,0,0,0,0,0,0}; *(bf16x8*)(hb + t*16) = z; }  // zero h

#define LDSFRAG(m,kf) (*(const bf16x8*)((char*)wlds + ((w*LW_FR + ((m)<2 ? ((m)*3+((kf)-5)) : (6+((m)-2)*2+((kf)-6))))*1024 + l*16)))
#define WFRAG(m,kf) (((kf) < (((m)<2)?5:6)) ? wf[m][kf] : LDSFRAG(m,kf))
#define HVREAD(kf) (*(const bf16x8*)(hb + ((lr*512 + (kf)*64 + lq*16) ^ ((lr&7)<<4))))

  const int lenc = lens[cgl];
  int blkLen = 0;
  for (int j=0;j<16;++j){ int v = lens[g*16+j]; blkLen = v>blkLen ? v : blkLen; }
  const int* vtc = vt + (size_t)cgl*COLCAP;
#define ENTW(j) (((j) < lenc) ? vtc[j] : DEADW)

  int e0 = ENTW(0), e1 = ENTW(1);
  const int goff = w*32 + lq*4;
  float c_[2][4] = {};
  uint2 gi[2], gg[2];
  {
    const ushort* gr = gx + ((size_t)((e0 & 511)*512 + bcol))*1024 + goff;
    gi[0]=*(const uint2*)(gr+  0); gi[1]=*(const uint2*)(gr+ 16);
    gg[0]=*(const uint2*)(gr+512); gg[1]=*(const uint2*)(gr+528);
  }
  __syncthreads();

  for (int k = 0; k < blkLen; ++k){
    const int e2 = ENTW(k+2);
    const ushort* grow0 = gx + ((size_t)((e0 & 511)*512 + bcol))*1024 + goff;
    uint2 gf0=*(const uint2*)(grow0+256), gf1=*(const uint2*)(grow0+272);
    uint2 go0=*(const uint2*)(grow0+768), go1=*(const uint2*)(grow0+784);
    // ---- pass 1: i and g gates (m-frags 0,1,4,5)
    f32x4 ai0={},ai1={},ag0={},ag1={};
    #pragma unroll
    for (int kf=0;kf<8;++kf){
      bf16x8 hv = HVREAD(kf);
      ai0 = __builtin_amdgcn_mfma_f32_16x16x32_bf16(WFRAG(0,kf), hv, ai0, 0,0,0);
      ai1 = __builtin_amdgcn_mfma_f32_16x16x32_bf16(WFRAG(1,kf), hv, ai1, 0,0,0);
      ag0 = __builtin_amdgcn_mfma_f32_16x16x32_bf16(WFRAG(4,kf), hv, ag0, 0,0,0);
      ag1 = __builtin_amdgcn_mfma_f32_16x16x32_bf16(WFRAG(5,kf), hv, ag1, 0,0,0);
    }
    float tig[2][4];
    #pragma unroll
    for (int hi=0;hi<2;++hi){
      uint2 ui = gi[hi], ug = gg[hi];
      float xi[4] = { b2f((unsigned short)(ui.x&0xffff)), b2f((unsigned short)(ui.x>>16)),
                      b2f((unsigned short)(ui.y&0xffff)), b2f((unsigned short)(ui.y>>16)) };
      float xg[4] = { b2f((unsigned short)(ug.x&0xffff)), b2f((unsigned short)(ug.x>>16)),
                      b2f((unsigned short)(ug.y&0xffff)), b2f((unsigned short)(ug.y>>16)) };
      #pragma unroll
      for (int r=0;r<4;++r){
        float iv = (hi ? ai1[r] : ai0[r]) + xi[r];
        float gv = (hi ? ag1[r] : ag0[r]) + xg[r];
        tig[hi][r] = sigf(iv) * tanhf_(gv);
      }
    }
    {
      const ushort* grow1 = gx + ((size_t)((e1 & 511)*512 + bcol))*1024 + goff;
      gi[0]=*(const uint2*)(grow1+  0); gi[1]=*(const uint2*)(grow1+ 16);
      gg[0]=*(const uint2*)(grow1+512); gg[1]=*(const uint2*)(grow1+528);
    }
    // ---- pass 2: f and o gates (m-frags 2,3,6,7)
    f32x4 af0={},af1={},ao0={},ao1={};
    #pragma unroll
    for (int kf=0;kf<8;++kf){
      bf16x8 hv = HVREAD(kf);
      af0 = __builtin_amdgcn_mfma_f32_16x16x32_bf16(WFRAG(2,kf), hv, af0, 0,0,0);
      af1 = __builtin_amdgcn_mfma_f32_16x16x32_bf16(WFRAG(3,kf), hv, af1, 0,0,0);
      ao0 = __builtin_amdgcn_mfma_f32_16x16x32_bf16(WFRAG(6,kf), hv, ao0, 0,0,0);
      ao1 = __builtin_amdgcn_mfma_f32_16x16x32_bf16(WFRAG(7,kf), hv, ao1, 0,0,0);
    }
    uint2 hpk[2];
    #pragma unroll
    for (int hi=0;hi<2;++hi){
      uint2 uf = hi ? gf1 : gf0, uo = hi ? go1 : go0;
      float xf[4] = { b2f((unsigned short)(uf.x&0xffff)), b2f((unsigned short)(uf.x>>16)),
                      b2f((unsigned short)(uf.y&0xffff)), b2f((unsigned short)(uf.y>>16)) };
      float xo[4] = { b2f((unsigned short)(uo.x&0xffff)), b2f((unsigned short)(uo.x>>16)),
                      b2f((unsigned short)(uo.y&0xffff)), b2f((unsigned short)(uo.y>>16)) };
      float hv[4];
      #pragma unroll
      for (int r=0;r<4;++r){
        float fv = (hi ? af1[r] : af0[r]) + xf[r];
        float ov = (hi ? ao1[r] : ao0[r]) + xo[r];
        float c = sigf(fv)*c_[hi][r] + tig[hi][r];
        c_[hi][r] = c;
        hv[r] = sigf(ov) * tanhf_(c);
      }
      hpk[hi].x = (unsigned)f2b(hv[0]) | ((unsigned)f2b(hv[1])<<16);
      hpk[hi].y = (unsigned)f2b(hv[2]) | ((unsigned)f2b(hv[3])<<16);
    }
    // ---- store hs (pre-mask) if active
    if (e0 & 512){
      ushort* hp = hsout + ((size_t)((e0 & 511)*512 + bcol))*256 + goff;
      *(uint2*)(hp +  0) = hpk[0];
      *(uint2*)(hp + 16) = hpk[1];
    }
    // ---- segment-boundary reset
    if (e0 & 1024){
      hpk[0].x=0; hpk[0].y=0; hpk[1].x=0; hpk[1].y=0;
      #pragma unroll
      for (int hi=0;hi<2;++hi)
        #pragma unroll
        for (int r=0;r<4;++r) c_[hi][r]=0.f;
    }
    e0 = e1; e1 = e2;
    BARRIER_LDS();   // all h reads of this step complete (no vmcnt drain)
    *(uint2*)(hb + ((lr*512 + w*64 +  0 + lq*8) ^ ((lr&7)<<4))) = hpk[0];
    *(uint2*)(hb + ((lr*512 + w*64 + 32 + lq*8) ^ ((lr&7)<<4))) = hpk[1];
    BARRIER_LDS();   // new h visible (no vmcnt drain)
  }
}

// ---------------- head: logits/values ----------------
__global__ __launch_bounds__(256) void head(
    const ushort* __restrict__ hs, const ushort* __restrict__ Wpv,
    const float* __restrict__ bpv, float* __restrict__ out){
  const int t = threadIdx.x, w = t>>6, l = t&63, lq = l>>4, lr = l&15;
  const int m0 = blockIdx.x*64 + w*16;
  f32x4 acc[2] = {};
  #pragma unroll
  for (int kf=0;kf<8;++kf){
    bf16x8 a = *(const bf16x8*)&hs[(size_t)(m0+lr)*256 + kf*32 + lq*8];
    #pragma unroll
    for (int j=0;j<2;++j){
      bf16x8 b = *(const bf16x8*)&Wpv[(size_t)(j*16+lr)*256 + kf*32 + lq*8];
      acc[j] = __builtin_amdgcn_mfma_f32_16x16x32_bf16(a, b, acc[j], 0,0,0);
    }
  }
  #pragma unroll
  for (int j=0;j<2;++j){
    const int n = j*16 + lr;
    if (n > 16) continue;
    const float bn = bpv[n];
    #pragma unroll
    for (int r=0;r<4;++r){
      const int m = m0 + lq*4 + r;
      float v = acc[j][r] + bn;
      if (n < 16) out[(size_t)m*16 + n] = v;
      else        out[(size_t)LOGOFF + m] = v;
    }
  }
}

// ---------------- launch ----------------
extern "C" void kernel_launch(void* const* d_in, const int* in_sizes, int n_in,
                              void* d_out, int out_size, void* d_ws, size_t ws_size,
                              hipStream_t stream) {
  const float* x    = (const float*)d_in[0];
  const float* rew  = (const float*)d_in[1];
  const float* W1   = (const float*)d_in[3];
  const float* b1   = (const float*)d_in[4];
  const float* Wih  = (const float*)d_in[5];
  const float* bih  = (const float*)d_in[6];
  const float* Whh  = (const float*)d_in[7];
  const float* bhh  = (const float*)d_in[8];
  const float* Wpi  = (const float*)d_in[9];
  const float* bpi  = (const float*)d_in[10];
  const float* Wv   = (const float*)d_in[11];
  const float* bv   = (const float*)d_in[12];
  const int*   la   = (const int*)d_in[13];
  const int*   dns  = (const int*)d_in[14];
  float* out = (float*)d_out;
  char* ws = (char*)d_ws;

  ushort* xbf  = (ushort*)(ws + 0LL);          // also reused for vt after gemm1
  int*    vt   = (int*)(ws + 0LL);             // 4096 cols x 256 x 4B = 4 MB
  int*    lens = (int*)(ws + 4194304LL);       // 16 KB
  ushort* h1   = (ushort*)(ws + 134217728LL);
  ushort* gx   = (ushort*)(ws + 402653184LL);
  ushort* hs   = (ushort*)(ws + 671088640LL);
  ushort* W1b  = (ushort*)(ws + 738197504LL);
  ushort* Awb  = (ushort*)(ws + 739246080LL);
  ushort* Whhb = (ushort*)(ws + 741343232LL);
  ushort* Wpvb = (ushort*)(ws + 741867520LL);
  float*  wr_  = (float*)(ws + 741883904LL);
  float*  bsum = (float*)(ws + 741888000LL);
  float*  Etab = (float*)(ws + 741892096LL);
  float*  bpv  = (float*)(ws + 741957632LL);

  (void)hipFuncSetAttribute((const void*)lstm_seq,
                            hipFuncAttributeMaxDynamicSharedMemorySize, 155648);

  prep_x<<<2048, 256, 0, stream>>>((const float4*)x, (short4v*)xbf);
  prep_w<<<4096, 256, 0, stream>>>(W1, Wih, bih, Whh, bhh, Wpi, bpi, Wv, bv,
                                   W1b, Awb, Whhb, Wpvb, wr_, bsum, Etab, bpv);
  gemm128<512,1><<<dim3(8,1024), 256, 0, stream>>>(xbf, W1b, h1, b1,
                                                   nullptr, nullptr, nullptr, nullptr);
  // builder overwrites the xbf region (gemm1 done with it; stream-ordered)
  build_cols<<<2, 256, 0, stream>>>(dns, vt, lens);
  gemm128<1024,2><<<dim3(8,1024), 256, 0, stream>>>(h1, Awb, gx, wr_, bsum, Etab, rew, la);
  lstm_seq<<<256, 512, 155648, stream>>>(Whhb, gx, hs, vt, lens);
  head<<<2048, 256, 0, stream>>>(hs, Wpvb, bpv, out);
}

// Round 7
// 1074.411 us; speedup vs baseline: 1.5535x; 1.5535x over previous
//
#include <hip/hip_runtime.h>

// Problem dims
#define S_LEN 256
#define B_SZ  512
#define IN_D  512
#define HID_D 1024
#define NA    16
#define LH    256
#define MR    131072           // S*B
#define LOGOFF 2097152         // S*B*A
#define COLCAP 256
#define DEADW  1024            // t=0, active=0, resetAfter=1

typedef __attribute__((ext_vector_type(8))) short bf16x8;
typedef __attribute__((ext_vector_type(4))) short short4v;
typedef __attribute__((ext_vector_type(4))) float f32x4;

__device__ __forceinline__ unsigned short f2b(float f){
  unsigned int u = __builtin_bit_cast(unsigned int, f);
  unsigned int r = (u + 0x7fffu + ((u>>16)&1u)) >> 16;
  return (unsigned short)r;
}
__device__ __forceinline__ float b2f(unsigned short b){
  unsigned int u = ((unsigned int)b)<<16; return __builtin_bit_cast(float,u);
}
__device__ __forceinline__ float sigf(float x){
  float t = exp2f(-1.4426950408889634f*x);
  return __builtin_amdgcn_rcpf(1.0f+t);
}
__device__ __forceinline__ float tanhf_(float x){
  float t = exp2f(2.8853900817779268f*x);
  return 1.0f - 2.0f*__builtin_amdgcn_rcpf(1.0f+t);
}

#define GLDS16(g, lp) __builtin_amdgcn_global_load_lds( \
    (const __attribute__((address_space(1))) unsigned int*)(g), \
    (__attribute__((address_space(3))) unsigned int*)(lp), 16, 0, 0)

// LDS-only barrier: no vmcnt drain.
#define BARRIER_LDS() do { \
    __builtin_amdgcn_sched_barrier(0); \
    asm volatile("s_waitcnt lgkmcnt(0)" ::: "memory"); \
    __builtin_amdgcn_s_barrier(); \
    __builtin_amdgcn_sched_barrier(0); \
  } while(0)

// ---------------- prep kernels ----------------
__global__ __launch_bounds__(256) void prep_x(const float4* __restrict__ x,
                                              short4v* __restrict__ xb){
  int i = blockIdx.x*256 + threadIdx.x;
  int stride = gridDim.x*256;
  for (; i < 16777216; i += stride){
    float4 f = x[i];
    short4v o; o[0]=(short)f2b(f.x); o[1]=(short)f2b(f.y); o[2]=(short)f2b(f.z); o[3]=(short)f2b(f.w);
    xb[i] = o;
  }
}

__global__ __launch_bounds__(256) void prep_w(
    const float* __restrict__ W1, const float* __restrict__ Wih,
    const float* __restrict__ bih, const float* __restrict__ Whh,
    const float* __restrict__ bhh, const float* __restrict__ Wpi,
    const float* __restrict__ bpi, const float* __restrict__ Wv,
    const float* __restrict__ bv,
    ushort* __restrict__ W1b, ushort* __restrict__ Awb, ushort* __restrict__ Whhb,
    ushort* __restrict__ Wpvb, float* __restrict__ wr_, float* __restrict__ bsum,
    float* __restrict__ Etab, float* __restrict__ bpv){
  int i = blockIdx.x*256 + threadIdx.x;
  if (i < 524288) W1b[i] = f2b(W1[i]);
  if (i < 1048576){ int n=i>>10, k=i&1023; Awb[i] = f2b(Wih[n*1041+k]); }
  if (i < 262144) Whhb[i] = f2b(Whh[i]);
  if (i < 8192){ int r=i>>8, k=i&255;
    float v = (r<16) ? Wpi[r*256+k] : ((r==16) ? Wv[k] : 0.f);
    Wpvb[i] = f2b(v); }
  if (i < 1024){ wr_[i] = Wih[i*1041+1024]; bsum[i] = bih[i]+bhh[i]; }
  if (i < 16384){ int a=i>>10, n=i&1023; Etab[i] = Wih[n*1041+1025+a]; }
  if (i < 32) bpv[i] = (i<16) ? bpi[i] : ((i==16) ? bv[0] : 0.f);
}

// ---------------- segment builder ----------------
__global__ __launch_bounds__(256) void build_cols(const int* __restrict__ dones,
                                                  int* __restrict__ vt,
                                                  int* __restrict__ lens){
  int b = blockIdx.x*256 + threadIdx.x;
  if (b >= 512) return;
  const int colbase = (b>>1)*16 + (b&1)*8;
  int cur = 0, curpos = 0;
  for (int t = 0; t < 256; ++t){
    int isStart = (t==0) || (dones[t*512+b] != 0);
    if (isStart){
      int nc = t>>5; if (nc>7) nc=7;      // cumulative position == t
      if (nc != cur){
        lens[colbase+cur] = curpos;
        for (int j=cur+1;j<nc;++j) lens[colbase+j]=0;
        cur = nc; curpos = 0;
      }
    }
    int rstA = (t==255) || (dones[(t==255?255:(t+1))*512+b] != 0);
    vt[(colbase+cur)*COLCAP + curpos] = t | (1<<9) | (rstA<<10);
    curpos++;
  }
  lens[colbase+cur] = curpos;
  for (int j=cur+1;j<8;++j) lens[colbase+j]=0;
}

// ---------------- 256x256 bf16 GEMM (BK=64, 8 waves, T2 swizzle, counted vmcnt) ----
// LDS 128KB: [buf p][A 32KB | B 32KB], row-major 128B rows, 16B-slot XOR (row&7)
// swizzle applied via inverse-swizzled GLOBAL source (glds dest linear, rule 21)
// and swizzled ds_read. Per K-tile: 2 phases {stage 4 glds -> vmcnt(4) ->
// 12 ds_read -> lgkm fence -> 32 MFMA @setprio}. vmcnt never 0 mid-loop (T4).
template<int K, int EPI>
__global__ __launch_bounds__(512, 2) void gemm256(
    const ushort* __restrict__ A, const ushort* __restrict__ Bm,
    ushort* __restrict__ C,
    const float* __restrict__ e0, const float* __restrict__ e1,
    const float* __restrict__ e2, const float* __restrict__ rew,
    const int* __restrict__ la){
  extern __shared__ char L[];
  const int t = threadIdx.x, w = t>>6, l = t&63, lq = l>>4, lr = l&15;
  const int wr = w>>2, wc = w&3;            // 2 x 4 wave grid
  const int lid = blockIdx.y*4 + blockIdx.x;
  const int xcd = lid & 7, jj = lid >> 3;   // XCD round-robin model
  const int m0 = (xcd*64 + (jj>>2))*256;
  const int n0 = (jj&3)*256;

  // Staging source (inverse swizzle): thread t covers LDS unit t of each 8KB
  // quarter; unit u -> row u>>3, stored slot u&7, content col-block (u&7)^(row&7).
  const int r0 = t>>3;
  const int c0 = (t&7) ^ (r0&7);
  const ushort* As0 = A  + (size_t)(m0 +       r0)*K + c0*8;
  const ushort* As1 = A  + (size_t)(m0 +  64 + r0)*K + c0*8;
  const ushort* As2 = A  + (size_t)(m0 + 128 + r0)*K + c0*8;
  const ushort* As3 = A  + (size_t)(m0 + 192 + r0)*K + c0*8;
  const ushort* Bs0 = Bm + (size_t)(n0 +       r0)*K + c0*8;
  const ushort* Bs1 = Bm + (size_t)(n0 +  64 + r0)*K + c0*8;
  const ushort* Bs2 = Bm + (size_t)(n0 + 128 + r0)*K + c0*8;
  const ushort* Bs3 = Bm + (size_t)(n0 + 192 + r0)*K + c0*8;

#define SA(p, ko) do{ \
    GLDS16(As0 + (ko), L + (p)*65536 +     0 + t*16); \
    GLDS16(As1 + (ko), L + (p)*65536 +  8192 + t*16); \
    GLDS16(As2 + (ko), L + (p)*65536 + 16384 + t*16); \
    GLDS16(As3 + (ko), L + (p)*65536 + 24576 + t*16); }while(0)
#define SB(p, ko) do{ \
    GLDS16(Bs0 + (ko), L + (p)*65536 + 32768 + t*16); \
    GLDS16(Bs1 + (ko), L + (p)*65536 + 40960 + t*16); \
    GLDS16(Bs2 + (ko), L + (p)*65536 + 49152 + t*16); \
    GLDS16(Bs3 + (ko), L + (p)*65536 + 57344 + t*16); }while(0)
// Frag reads (swizzled): row R at R*128B, col-block cb at slot cb^(R&7).
// R&7 == lr&7 for all fragments (16-aligned bases), 2 lanes/slot -> free.
#define LDA(p, mf, ks) (*(const bf16x8*)(L + (p)*65536 + \
    (wr*128 + (mf)*16 + lr)*128 + (((((ks)*4) + lq) ^ (lr&7))<<4)))
#define LDB(p, nf, ks) (*(const bf16x8*)(L + (p)*65536 + 32768 + \
    (wc*64 + (nf)*16 + lr)*128 + (((((ks)*4) + lq) ^ (lr&7))<<4)))

  f32x4 acc[8][4] = {};
  constexpr int NT = K/64;

  SA(0, 0); SB(0, 0);          // prologue: 8 loads in flight
  #pragma unroll
  for (int kt = 0; kt < NT; ++kt){
    const int p = kt&1;
    // ---- phase 0: stage next A early, counted wait, ksub0 compute
    if (kt+1 < NT) SA(p^1, (kt+1)*64);
    __builtin_amdgcn_sched_barrier(0);
    if (kt+1 < NT) asm volatile("s_waitcnt vmcnt(4)" ::: "memory");
    else           asm volatile("s_waitcnt vmcnt(0)" ::: "memory");
    __builtin_amdgcn_s_barrier();
    __builtin_amdgcn_sched_barrier(0);
    bf16x8 af[8], bf[4];
    #pragma unroll
    for (int mf=0;mf<8;++mf) af[mf] = LDA(p, mf, 0);
    #pragma unroll
    for (int nf=0;nf<4;++nf) bf[nf] = LDB(p, nf, 0);
    asm volatile("s_waitcnt lgkmcnt(0)" ::: "memory");
    __builtin_amdgcn_sched_barrier(0);
    __builtin_amdgcn_s_setprio(1);
    #pragma unroll
    for (int mf=0;mf<8;++mf)
      #pragma unroll
      for (int nf=0;nf<4;++nf)
        acc[mf][nf] = __builtin_amdgcn_mfma_f32_16x16x32_bf16(bf[nf], af[mf], acc[mf][nf], 0,0,0);
    __builtin_amdgcn_s_setprio(0);
    // ---- phase 1: stage next B, ksub1 compute
    if (kt+1 < NT) SB(p^1, (kt+1)*64);
    #pragma unroll
    for (int mf=0;mf<8;++mf) af[mf] = LDA(p, mf, 1);
    #pragma unroll
    for (int nf=0;nf<4;++nf) bf[nf] = LDB(p, nf, 1);
    asm volatile("s_waitcnt lgkmcnt(0)" ::: "memory");
    __builtin_amdgcn_sched_barrier(0);
    __builtin_amdgcn_s_setprio(1);
    #pragma unroll
    for (int mf=0;mf<8;++mf)
      #pragma unroll
      for (int nf=0;nf<4;++nf)
        acc[mf][nf] = __builtin_amdgcn_mfma_f32_16x16x32_bf16(bf[nf], af[mf], acc[mf][nf], 0,0,0);
    __builtin_amdgcn_s_setprio(0);
    // end-of-iter: all waves' reads of buf[p] done before next iter's stages
    __builtin_amdgcn_sched_barrier(0);
    __builtin_amdgcn_s_barrier();
    __builtin_amdgcn_sched_barrier(0);
  }

  // Swapped-operand C/D mapping (R6-verified): m = ..+mf*16+lr (lane-fixed),
  // n = ..+nf*16+lq*4+r (4 consecutive) -> 8B stores.
  if (EPI == 1){
    #pragma unroll
    for (int nf=0; nf<4; ++nf){
      const int nb = n0 + wc*64 + nf*16 + lq*4;
      const float4 bn = *(const float4*)&e0[nb];
      #pragma unroll
      for (int mf=0; mf<8; ++mf){
        const int m = m0 + wr*128 + mf*16 + lr;
        short4v v;
        #pragma unroll
        for (int r=0;r<4;++r){
          float vv = acc[mf][nf][r] + ((const float*)&bn)[r];
          vv = vv > 0.f ? vv : 0.01f*vv;
          v[r] = (short)f2b(vv);
        }
        *(short4v*)&C[(size_t)m*1024 + nb] = v;
      }
    }
  } else {
    #pragma unroll
    for (int mf=0; mf<8; ++mf){
      const int m = m0 + wr*128 + mf*16 + lr;
      const float rv = rew[m];
      const int av = la[m];
      #pragma unroll
      for (int nf=0; nf<4; ++nf){
        const int nb = n0 + wc*64 + nf*16 + lq*4;
        const float4 wv = *(const float4*)&e0[nb];
        const float4 bs = *(const float4*)&e1[nb];
        const float4 et = *(const float4*)&e2[(size_t)av*1024 + nb];
        short4v v;
        #pragma unroll
        for (int r=0;r<4;++r){
          float vv = acc[mf][nf][r] + rv*((const float*)&wv)[r]
                   + ((const float*)&et)[r] + ((const float*)&bs)[r];
          v[r] = (short)f2b(vv);
        }
        *(short4v*)&C[(size_t)m*1024 + nb] = v;
      }
    }
  }
#undef SA
#undef SB
#undef LDA
#undef LDB
}

// ---------------- recurrent LSTM kernel (segment-parallel) ----------------
#define LW_FR 18
#define HB0 (8*LW_FR*1024)
__global__ __launch_bounds__(512, 2) void lstm_seq(
    const ushort* __restrict__ Whhb, const ushort* __restrict__ gx,
    ushort* __restrict__ hsout, const int* __restrict__ vt,
    const int* __restrict__ lens){
  extern __shared__ char smem[];
  ushort* wlds = (ushort*)smem;
  char* hb = smem + HB0;                 // 16 cols x 256 bf16, XOR-swizzled
  const int t = threadIdx.x, w = t>>6, l = t&63, lq = l>>4, lr = l&15;
  const int g = blockIdx.x;
  const int bcol = 2*g + (lr>>3);        // batch of column lr
  const int cgl = g*16 + lr;             // global column id

  // register weight frags: m<2 -> k0..4 ; m>=2 -> k0..5   (m = gate*2+hi)
  bf16x8 wf[8][6];
  #pragma unroll
  for (int m=0;m<8;++m){
    const size_t rb = (size_t)((m>>1)*256 + w*32 + (m&1)*16 + lr)*256 + lq*8;
    #pragma unroll
    for (int k=0;k<6;++k){
      if (k < ((m<2)?5:6)) wf[m][k] = *(const bf16x8*)&Whhb[rb + (size_t)k*32];
    }
  }
  // Pin: forbid rematerializing these loads inside the step loop.
  #pragma unroll
  for (int m=0;m<8;++m)
    #pragma unroll
    for (int k=0;k<6;++k)
      if (k < ((m<2)?5:6)) asm volatile("" : "+v"(wf[m][k]));

  // LDS weight frags: m<2 -> k5,6,7 ; m>=2 -> k6,7
  #pragma unroll
  for (int m=0;m<8;++m){
    const size_t rb = (size_t)((m>>1)*256 + w*32 + (m&1)*16 + lr)*256 + lq*8;
    #pragma unroll
    for (int kk=0;kk<3;++kk){
      if (kk < ((m<2)?3:2)){
        const int k  = (m<2)?(5+kk):(6+kk);
        const int fi = (m<2)?(m*3+kk):(6+(m-2)*2+kk);
        bf16x8 v = *(const bf16x8*)&Whhb[rb + (size_t)k*32];
        *(bf16x8*)((char*)wlds + ((w*LW_FR + fi)*1024 + l*16)) = v;
      }
    }
  }
  { bf16x8 z = {0,0,0,0,0,0,0,0}; *(bf16x8*)(hb + t*16) = z; }  // zero h

#define LDSFRAG(m,kf) (*(const bf16x8*)((char*)wlds + ((w*LW_FR + ((m)<2 ? ((m)*3+((kf)-5)) : (6+((m)-2)*2+((kf)-6))))*1024 + l*16)))
#define WFRAG(m,kf) (((kf) < (((m)<2)?5:6)) ? wf[m][kf] : LDSFRAG(m,kf))
#define HVREAD(kf) (*(const bf16x8*)(hb + ((lr*512 + (kf)*64 + lq*16) ^ ((lr&7)<<4))))

  const int lenc = lens[cgl];
  int blkLen = 0;
  for (int j=0;j<16;++j){ int v = lens[g*16+j]; blkLen = v>blkLen ? v : blkLen; }
  const int* vtc = vt + (size_t)cgl*COLCAP;
#define ENTW(j) (((j) < lenc) ? vtc[j] : DEADW)

  int e0 = ENTW(0), e1 = ENTW(1);
  const int goff = w*32 + lq*4;
  float c_[2][4] = {};
  uint2 gi[2], gg[2];
  {
    const ushort* gr = gx + ((size_t)((e0 & 511)*512 + bcol))*1024 + goff;
    gi[0]=*(const uint2*)(gr+  0); gi[1]=*(const uint2*)(gr+ 16);
    gg[0]=*(const uint2*)(gr+512); gg[1]=*(const uint2*)(gr+528);
  }
  __syncthreads();

  for (int k = 0; k < blkLen; ++k){
    const int e2 = ENTW(k+2);
    const ushort* grow0 = gx + ((size_t)((e0 & 511)*512 + bcol))*1024 + goff;
    uint2 gf0=*(const uint2*)(grow0+256), gf1=*(const uint2*)(grow0+272);
    uint2 go0=*(const uint2*)(grow0+768), go1=*(const uint2*)(grow0+784);
    // ---- pass 1: i and g gates (m-frags 0,1,4,5)
    f32x4 ai0={},ai1={},ag0={},ag1={};
    #pragma unroll
    for (int kf=0;kf<8;++kf){
      bf16x8 hv = HVREAD(kf);
      ai0 = __builtin_amdgcn_mfma_f32_16x16x32_bf16(WFRAG(0,kf), hv, ai0, 0,0,0);
      ai1 = __builtin_amdgcn_mfma_f32_16x16x32_bf16(WFRAG(1,kf), hv, ai1, 0,0,0);
      ag0 = __builtin_amdgcn_mfma_f32_16x16x32_bf16(WFRAG(4,kf), hv, ag0, 0,0,0);
      ag1 = __builtin_amdgcn_mfma_f32_16x16x32_bf16(WFRAG(5,kf), hv, ag1, 0,0,0);
    }
    float tig[2][4];
    #pragma unroll
    for (int hi=0;hi<2;++hi){
      uint2 ui = gi[hi], ug = gg[hi];
      float xi[4] = { b2f((unsigned short)(ui.x&0xffff)), b2f((unsigned short)(ui.x>>16)),
                      b2f((unsigned short)(ui.y&0xffff)), b2f((unsigned short)(ui.y>>16)) };
      float xg[4] = { b2f((unsigned short)(ug.x&0xffff)), b2f((unsigned short)(ug.x>>16)),
                      b2f((unsigned short)(ug.y&0xffff)), b2f((unsigned short)(ug.y>>16)) };
      #pragma unroll
      for (int r=0;r<4;++r){
        float iv = (hi ? ai1[r] : ai0[r]) + xi[r];
        float gv = (hi ? ag1[r] : ag0[r]) + xg[r];
        tig[hi][r] = sigf(iv) * tanhf_(gv);
      }
    }
    {
      const ushort* grow1 = gx + ((size_t)((e1 & 511)*512 + bcol))*1024 + goff;
      gi[0]=*(const uint2*)(grow1+  0); gi[1]=*(const uint2*)(grow1+ 16);
      gg[0]=*(const uint2*)(grow1+512); gg[1]=*(const uint2*)(grow1+528);
    }
    // ---- pass 2: f and o gates (m-frags 2,3,6,7)
    f32x4 af0={},af1={},ao0={},ao1={};
    #pragma unroll
    for (int kf=0;kf<8;++kf){
      bf16x8 hv = HVREAD(kf);
      af0 = __builtin_amdgcn_mfma_f32_16x16x32_bf16(WFRAG(2,kf), hv, af0, 0,0,0);
      af1 = __builtin_amdgcn_mfma_f32_16x16x32_bf16(WFRAG(3,kf), hv, af1, 0,0,0);
      ao0 = __builtin_amdgcn_mfma_f32_16x16x32_bf16(WFRAG(6,kf), hv, ao0, 0,0,0);
      ao1 = __builtin_amdgcn_mfma_f32_16x16x32_bf16(WFRAG(7,kf), hv, ao1, 0,0,0);
    }
    uint2 hpk[2];
    #pragma unroll
    for (int hi=0;hi<2;++hi){
      uint2 uf = hi ? gf1 : gf0, uo = hi ? go1 : go0;
      float xf[4] = { b2f((unsigned short)(uf.x&0xffff)), b2f((unsigned short)(uf.x>>16)),
                      b2f((unsigned short)(uf.y&0xffff)), b2f((unsigned short)(uf.y>>16)) };
      float xo[4] = { b2f((unsigned short)(uo.x&0xffff)), b2f((unsigned short)(uo.x>>16)),
                      b2f((unsigned short)(uo.y&0xffff)), b2f((unsigned short)(uo.y>>16)) };
      float hv[4];
      #pragma unroll
      for (int r=0;r<4;++r){
        float fv = (hi ? af1[r] : af0[r]) + xf[r];
        float ov = (hi ? ao1[r] : ao0[r]) + xo[r];
        float c = sigf(fv)*c_[hi][r] + tig[hi][r];
        c_[hi][r] = c;
        hv[r] = sigf(ov) * tanhf_(c);
      }
      hpk[hi].x = (unsigned)f2b(hv[0]) | ((unsigned)f2b(hv[1])<<16);
      hpk[hi].y = (unsigned)f2b(hv[2]) | ((unsigned)f2b(hv[3])<<16);
    }
    // ---- store hs (pre-mask) if active
    if (e0 & 512){
      ushort* hp = hsout + ((size_t)((e0 & 511)*512 + bcol))*256 + goff;
      *(uint2*)(hp +  0) = hpk[0];
      *(uint2*)(hp + 16) = hpk[1];
    }
    // ---- segment-boundary reset
    if (e0 & 1024){
      hpk[0].x=0; hpk[0].y=0; hpk[1].x=0; hpk[1].y=0;
      #pragma unroll
      for (int hi=0;hi<2;++hi)
        #pragma unroll
        for (int r=0;r<4;++r) c_[hi][r]=0.f;
    }
    e0 = e1; e1 = e2;
    BARRIER_LDS();   // all h reads of this step complete (no vmcnt drain)
    *(uint2*)(hb + ((lr*512 + w*64 +  0 + lq*8) ^ ((lr&7)<<4))) = hpk[0];
    *(uint2*)(hb + ((lr*512 + w*64 + 32 + lq*8) ^ ((lr&7)<<4))) = hpk[1];
    BARRIER_LDS();   // new h visible (no vmcnt drain)
  }
}

// ---------------- head: logits/values ----------------
__global__ __launch_bounds__(256) void head(
    const ushort* __restrict__ hs, const ushort* __restrict__ Wpv,
    const float* __restrict__ bpv, float* __restrict__ out){
  const int t = threadIdx.x, w = t>>6, l = t&63, lq = l>>4, lr = l&15;
  const int m0 = blockIdx.x*64 + w*16;
  f32x4 acc[2] = {};
  #pragma unroll
  for (int kf=0;kf<8;++kf){
    bf16x8 a = *(const bf16x8*)&hs[(size_t)(m0+lr)*256 + kf*32 + lq*8];
    #pragma unroll
    for (int j=0;j<2;++j){
      bf16x8 b = *(const bf16x8*)&Wpv[(size_t)(j*16+lr)*256 + kf*32 + lq*8];
      acc[j] = __builtin_amdgcn_mfma_f32_16x16x32_bf16(a, b, acc[j], 0,0,0);
    }
  }
  #pragma unroll
  for (int j=0;j<2;++j){
    const int n = j*16 + lr;
    if (n > 16) continue;
    const float bn = bpv[n];
    #pragma unroll
    for (int r=0;r<4;++r){
      const int m = m0 + lq*4 + r;
      float v = acc[j][r] + bn;
      if (n < 16) out[(size_t)m*16 + n] = v;
      else        out[(size_t)LOGOFF + m] = v;
    }
  }
}

// ---------------- launch ----------------
extern "C" void kernel_launch(void* const* d_in, const int* in_sizes, int n_in,
                              void* d_out, int out_size, void* d_ws, size_t ws_size,
                              hipStream_t stream) {
  const float* x    = (const float*)d_in[0];
  const float* rew  = (const float*)d_in[1];
  const float* W1   = (const float*)d_in[3];
  const float* b1   = (const float*)d_in[4];
  const float* Wih  = (const float*)d_in[5];
  const float* bih  = (const float*)d_in[6];
  const float* Whh  = (const float*)d_in[7];
  const float* bhh  = (const float*)d_in[8];
  const float* Wpi  = (const float*)d_in[9];
  const float* bpi  = (const float*)d_in[10];
  const float* Wv   = (const float*)d_in[11];
  const float* bv   = (const float*)d_in[12];
  const int*   la   = (const int*)d_in[13];
  const int*   dns  = (const int*)d_in[14];
  float* out = (float*)d_out;
  char* ws = (char*)d_ws;

  ushort* xbf  = (ushort*)(ws + 0LL);          // also reused for vt after gemm1
  int*    vt   = (int*)(ws + 0LL);             // 4096 cols x 256 x 4B = 4 MB
  int*    lens = (int*)(ws + 4194304LL);       // 16 KB
  ushort* h1   = (ushort*)(ws + 134217728LL);
  ushort* gx   = (ushort*)(ws + 402653184LL);
  ushort* hs   = (ushort*)(ws + 671088640LL);
  ushort* W1b  = (ushort*)(ws + 738197504LL);
  ushort* Awb  = (ushort*)(ws + 739246080LL);
  ushort* Whhb = (ushort*)(ws + 741343232LL);
  ushort* Wpvb = (ushort*)(ws + 741867520LL);
  float*  wr_  = (float*)(ws + 741883904LL);
  float*  bsum = (float*)(ws + 741888000LL);
  float*  Etab = (float*)(ws + 741892096LL);
  float*  bpv  = (float*)(ws + 741957632LL);

  (void)hipFuncSetAttribute((const void*)lstm_seq,
                            hipFuncAttributeMaxDynamicSharedMemorySize, 155648);
  auto g1 = &gemm256<512,1>;
  auto g2 = &gemm256<1024,2>;
  (void)hipFuncSetAttribute((const void*)g1,
                            hipFuncAttributeMaxDynamicSharedMemorySize, 131072);
  (void)hipFuncSetAttribute((const void*)g2,
                            hipFuncAttributeMaxDynamicSharedMemorySize, 131072);

  prep_x<<<2048, 256, 0, stream>>>((const float4*)x, (short4v*)xbf);
  prep_w<<<4096, 256, 0, stream>>>(W1, Wih, bih, Whh, bhh, Wpi, bpi, Wv, bv,
                                   W1b, Awb, Whhb, Wpvb, wr_, bsum, Etab, bpv);
  gemm256<512,1><<<dim3(4,512), 512, 131072, stream>>>(xbf, W1b, h1, b1,
                                                       nullptr, nullptr, nullptr, nullptr);
  // builder overwrites the xbf region (gemm1 done with it; stream-ordered)
  build_cols<<<2, 256, 0, stream>>>(dns, vt, lens);
  gemm256<1024,2><<<dim3(4,512), 512, 131072, stream>>>(h1, Awb, gx, wr_, bsum, Etab, rew, la);
  lstm_seq<<<256, 512, 155648, stream>>>(Whhb, gx, hs, vt, lens);
  head<<<2048, 256, 0, stream>>>(hs, Wpvb, bpv, out);
}